// Round 1
// 234.537 us; speedup vs baseline: 1.0672x; 1.0672x over previous
//
#include <hip/hip_runtime.h>

// SpectralConv2d DHT spectral conv, B=16, Cin=Cout=64, H=W=128, modes 20x20.
// All stages linear; blurs folded into bases/weights.
//   fwd:  X(k1,k2) = sum_n1 [cos(th k1 n1) Pc - sin(th k1 n1) Ps
//                            - sin(th k1(n1+1)) Pc1 - cos(th k1(n1+1)) Ps1]
//   inv (rank-42): y(u,v) = sum_{A=0..20} cosb(u,A)*RsC[A][v] + sinb(u,A)*RsS[A][v]
// Kernels:
//  kinit(3 blocks): L2g/RB2g (42x128 inverse bases), Tg (128x40), Lf2g (20x512)
//  k0a: blur w1 over Cout + transpose -> wbT;  k0b: Wp/Wm combine
//  k12: FUSED per (b,c). v2: 40960B LDS union (Tgs+xs | Pm2-swizzled),
//       256-thread 4x5 phase-1 tile, b128 conflict-free A reads, 200-thread combine.
//  k3:  grid (m x 4 b-groups): batch-blur folded into staging; O[b,o,m]
//  k5b: per (b,o): Rs2[42][128] in LDS, Y = L2 * Rs2

#define TWO_PI 6.283185307179586f
#define THETA (TWO_PI / 128.0f)

__device__ __forceinline__ void gauss9(float* g) {
  float s = 0.f;
#pragma unroll
  for (int t = 0; t < 9; ++t) { float d = (float)(t - 4); g[t] = expf(-0.5f * d * d); s += g[t]; }
  float inv = 1.f / s;
#pragma unroll
  for (int t = 0; t < 9; ++t) g[t] *= inv;
}

// ---- kinit: b0: L2g+RB2g (42x128 each), b1: Tg, b2: Lf2g
__global__ void kinit(float* __restrict__ L2g, float* __restrict__ RB2g,
                      float* __restrict__ Tg, float* __restrict__ Lf2g) {
  __shared__ float raw[128][44];
  int tid = threadIdx.x;
  int blk = blockIdx.x;
  if (blk == 1) {
    for (int i = tid; i < 5120; i += 256) {
      int n2 = i / 40, col = i - n2 * 40;
      int k2 = (col < 20) ? col : col - 20;
      float a = (float)((k2 * n2) & 127) * THETA;
      Tg[i] = (col < 20) ? cosf(a) : sinf(a);
    }
    return;
  }
  if (blk == 2) {
    for (int i = tid; i < 10240; i += 256) {
      int k1 = i >> 9, t = i & 511;
      int q = t >> 7, n1 = t & 127;
      int nn = n1 + ((q >= 2) ? 1 : 0);
      float a = (float)((k1 * nn) & 127) * THETA;
      float v;
      if (q == 0) v = cosf(a);
      else if (q == 1) v = -sinf(a);
      else if (q == 2) v = -sinf(a);
      else v = -cosf(a);
      Lf2g[i] = v;
    }
    return;
  }
  // block 0: rank-42 bases. rows 0..20 = cos(th u A), 21..41 = sin(th u A)
  for (int i = tid; i < 5376; i += 256) {
    int u = i / 42, t = i - u * 42;
    int A = (t < 21) ? t : t - 21;
    float a = (float)((u * A) & 127) * THETA;
    raw[u][t] = (t < 21) ? cosf(a) : sinf(a);
  }
  __syncthreads();
  float g[9]; gauss9(g);
  for (int i = tid; i < 5376; i += 256) {
    int u = i / 42, t = i - u * 42;
    float acc = 0.f;
#pragma unroll
    for (int tp = 0; tp < 9; ++tp) {
      int uc = u - 4 + tp; uc = uc < 0 ? 0 : (uc > 127 ? 127 : uc);
      acc += g[tp] * raw[uc][t];
    }
    L2g[t * 128 + u] = acc;
    bool keep = (u <= 32) || (u >= 96);
    RB2g[t * 128 + u] = keep ? acc : 0.f;
  }
}

// ---- k0a: blur w1 over Cout + transpose: wbT[(c*400+m)*64+o]
__global__ void k0a_blurT(const float* __restrict__ w1, float* __restrict__ wbT) {
  __shared__ float tile[64][69];
  int c = blockIdx.x / 7, chunk = blockIdx.x % 7;
  int m0 = chunk * 64;
  int mw = 400 - m0; if (mw > 64) mw = 64;
  int tid = threadIdx.x;
  for (int t = tid; t < 4096; t += 256) {
    int o = t >> 6, mm = t & 63;
    tile[o][mm] = (mm < mw) ? w1[(c * 64 + o) * 400 + m0 + mm] : 0.f;
  }
  __syncthreads();
  float g[9]; gauss9(g);
  for (int t = tid; t < 4096; t += 256) {
    int mm = t >> 6, o = t & 63;
    if (mm >= mw) continue;
    float acc = 0.f;
#pragma unroll
    for (int tp = 0; tp < 9; ++tp) {
      int oc = o - 4 + tp; oc = oc < 0 ? 0 : (oc > 63 ? 63 : oc);
      acc += g[tp] * tile[oc][mm];
    }
    wbT[(c * 400 + m0 + mm) * 64 + o] = acc;
  }
}

// ---- k0b: Wp/Wm[(m*64+c)*64+o] = sc*(wbT[c][m][o] +/- wbT[c][nm][o])
__global__ void k0b_combine(const float* __restrict__ wbT, float* __restrict__ Wp,
                            float* __restrict__ Wm) {
  int m = blockIdx.x;
  int i = m / 20, j = m - i * 20;
  int nm = ((20 - i) % 20) * 20 + ((20 - j) % 20);
  int tid = threadIdx.x;
  const float sc = 0.5f / 16384.0f;
  for (int t = tid; t < 4096; t += 256) {
    int c = t >> 6, o = t & 63;
    float a = wbT[(c * 400 + m) * 64 + o];
    float b = wbT[(c * 400 + nm) * 64 + o];
    Wp[(m * 64 + c) * 64 + o] = (a + b) * sc;
    Wm[(m * 64 + c) * 64 + o] = (a - b) * sc;
  }
}

// ---- k12 v2: fused forward transform + mode combine. One block per (b,c).
// LDS union (40960 B exactly -> 4 blocks/CU):
//   phase 1: [0..5120)   Tgs (staged Tg, 128x40)
//            [5120..9344) xs  (32 n2-rows x 132, 16B-aligned rows -> b128 A reads)
//   phase 2: [0..10240)  Pm2 (20 rows x 512, chunk-XOR swizzle c ^= ((k2>>1)&7)<<2)
// Phase 1: 256 threads, 4 rows x 5 cols per thread (32 rgrp x 8 cgrp).
// Phase 2: rotation (sincosf, no ct table) then 200-thread combine, 2 outputs each.
__global__ void __launch_bounds__(256, 4) k12(const float* __restrict__ x,
                                              const float* __restrict__ Tg,
                                              const float* __restrict__ Lf2g,
                                              float* __restrict__ X1) {
  __shared__ float lds[10240];   // 40960 B
  int bc = blockIdx.x, tid = threadIdx.x;
  const float* xb = x + (long)bc * 16384;

  // stage Tg once (5120 floats, coalesced)
  for (int t = tid; t < 5120; t += 256) lds[t] = Tg[t];

  int rg = tid & 31, cg = tid >> 5;   // 32 row-groups x 8 col-groups
  int r0 = rg * 4, c0 = cg * 5;
  float acc[4][5];
#pragma unroll
  for (int i = 0; i < 4; ++i)
#pragma unroll
    for (int j = 0; j < 5; ++j) acc[i][j] = 0.f;

  float* xs = lds + 5120;             // [32][132]
  for (int ch = 0; ch < 4; ++ch) {
    __syncthreads();
    // stage 128 n1 x 32 n2 transposed; global reads coalesced (2x128B per wave)
    for (int t = tid; t < 4096; t += 256) {
      int n1 = t >> 5, n2l = t & 31;
      xs[n2l * 132 + n1] = xb[n1 * 128 + ch * 32 + n2l];
    }
    __syncthreads();
#pragma unroll 4
    for (int k = 0; k < 32; ++k) {
      float4 av = *(const float4*)&xs[k * 132 + r0];        // conflict-free b128
      const float* tr = lds + (ch * 32 + k) * 40 + c0;      // 2-addr broadcast
      float avv[4] = {av.x, av.y, av.z, av.w};
      float bvv[5] = {tr[0], tr[1], tr[2], tr[3], tr[4]};
#pragma unroll
      for (int i = 0; i < 4; ++i)
#pragma unroll
        for (int j = 0; j < 5; ++j) acc[i][j] += avv[i] * bvv[j];
    }
  }
  __syncthreads();
  // scatter acc into swizzled Pm2 (overwrites Tgs/xs; all reads done at barrier)
#pragma unroll
  for (int j = 0; j < 5; ++j) {
    int col = c0 + j;
    int k2 = (col < 20) ? col : col - 20;
    int part = (col < 20) ? 0 : 128;
    int m = ((k2 >> 1) & 7) << 2;
    float* row = lds + k2 * 512;
#pragma unroll
    for (int i = 0; i < 4; ++i)
      row[(part + r0 + i) ^ m] = acc[i][j];
  }
  __syncthreads();
  // rotation: Pc1/Ps1 = one-sample phase shift of Pc/Ps
  for (int t = tid; t < 2560; t += 256) {
    int k2 = t >> 7, n1 = t & 127;
    int m = ((k2 >> 1) & 7) << 2;
    float* row = lds + k2 * 512;
    float pc = row[n1 ^ m], ps = row[(128 + n1) ^ m];
    float ck, sk;
    sincosf(THETA * (float)k2, &sk, &ck);
    row[(256 + n1) ^ m] = ck * pc - sk * ps;
    row[(384 + n1) ^ m] = sk * pc + ck * ps;
  }
  __syncthreads();
  // combine: X1[k1][k2] = Lf2g[k1] . Pm2[k2]; 200 threads, 2 outputs each
  if (tid < 200) {
    int k1 = tid / 10, k2 = (tid % 10) * 2;
    int m = ((k2 >> 1) & 7) << 2;           // same for k2 and k2+1
    const float* p0r = lds + k2 * 512;
    const float* p1r = lds + (k2 + 1) * 512;
    const float* lrow = Lf2g + k1 * 512;
    float a0 = 0.f, a1 = 0.f;
    for (int t = 0; t < 512; t += 4) {
      float4 l = *(const float4*)(lrow + t);
      int ts = t ^ m;                       // chunk-aligned (m has only bits 2..4)
      float4 p0 = *(const float4*)(p0r + ts);
      float4 p1 = *(const float4*)(p1r + ts);
      a0 += l.x * p0.x + l.y * p0.y + l.z * p0.z + l.w * p0.w;
      a1 += l.x * p1.x + l.y * p1.y + l.z * p1.z + l.w * p1.w;
    }
    X1[(k1 * 20 + k2) * 1024 + bc] = a0;
    X1[(k1 * 20 + k2 + 1) * 1024 + bc] = a1;
  }
}

// ---- k3 v2: grid (m*4 + bq); batch-blur folded into staging. O[(b*64+o)*400+m]
__global__ void k3_mix(const float* __restrict__ X1, const float* __restrict__ Wp,
                       const float* __restrict__ Wm, float* __restrict__ O) {
  __shared__ float Xa[4][64], Xn[4][64];
  int m = blockIdx.x >> 2, bq = blockIdx.x & 3;
  int i = m / 20, j = m - i * 20;
  int nm = ((20 - i) % 20) * 20 + ((20 - j) % 20);
  int tid = threadIdx.x;
  float g[9]; gauss9(g);
  {
    int bl = tid >> 6, c = tid & 63;
    int b = bq * 4 + bl;
    float sa = 0.f, sn = 0.f;
#pragma unroll
    for (int tp = 0; tp < 9; ++tp) {
      int bb = b - 4 + tp; bb = bb < 0 ? 0 : (bb > 15 ? 15 : bb);
      sa += g[tp] * X1[m * 1024 + bb * 64 + c];
      sn += g[tp] * X1[nm * 1024 + bb * 64 + c];
    }
    Xa[bl][c] = sa; Xn[bl][c] = sn;
  }
  __syncthreads();
  int o = tid & 63, bl = tid >> 6;
  int b = bq * 4 + bl;
  float acc = 0.f;
#pragma unroll 4
  for (int c = 0; c < 64; ++c) {
    float wp = Wp[(m * 64 + c) * 64 + o];
    float wm = Wm[(m * 64 + c) * 64 + o];
    acc += Xa[bl][c] * wp + Xn[bl][c] * wm;
  }
  O[(b * 64 + o) * 400 + m] = acc;
}

// ---- k5b: per (b,o): Rs2[42][128] (C rows 0..20, S rows 21..41), Y = L2 * Rs2
__global__ void __launch_bounds__(256) k5b_final(const float* __restrict__ O,
                                                 const float* __restrict__ L2g,
                                                 const float* __restrict__ RB2g,
                                                 float* __restrict__ out) {
  __shared__ float Os[400];
  __shared__ float Rs[42 * 128];
  int bo = blockIdx.x, tid = threadIdx.x;
  for (int t = tid; t < 400; t += 256) Os[t] = O[bo * 400 + t];
  __syncthreads();
  const float4* Bc4 = (const float4*)RB2g;             // rows 0..20
  const float4* Bs4 = (const float4*)(RB2g + 21 * 128);
  for (int task = tid; task < 1344; task += 256) {
    int r = task >> 5, vq = task & 31;
    bool isS = (r >= 21);
    int A = isS ? (r - 21) : r;
    float4 acc = make_float4(0.f, 0.f, 0.f, 0.f);
    if (A < 20) {
      const float4* Bm = isS ? Bs4 : Bc4;
      float sgn = isS ? -1.f : 1.f;
#pragma unroll
      for (int k2 = 0; k2 < 20; ++k2) {
        float ov = sgn * Os[A * 20 + k2];
        float4 b = Bm[k2 * 32 + vq];
        acc.x += ov * b.x; acc.y += ov * b.y; acc.z += ov * b.z; acc.w += ov * b.w;
      }
    }
    if (A >= 1) {
      const float4* Bm = isS ? Bc4 : Bs4;
#pragma unroll
      for (int k2 = 0; k2 < 20; ++k2) {
        float ov = Os[(A - 1) * 20 + k2];
        float4 b = Bm[(k2 + 1) * 32 + vq];
        acc.x -= ov * b.x; acc.y -= ov * b.y; acc.z -= ov * b.z; acc.w -= ov * b.w;
      }
    }
    *(float4*)&Rs[r * 128 + vq * 4] = acc;
  }
  __syncthreads();
  int ug = tid >> 4, vg = tid & 15;
  int u0 = ug * 8, v0 = vg * 4;   // v-cols: v0..v0+3 and 64+v0..64+v0+3
  float acc[8][8];
#pragma unroll
  for (int i = 0; i < 8; ++i)
#pragma unroll
    for (int j = 0; j < 8; ++j) acc[i][j] = 0.f;
  for (int r = 0; r < 42; ++r) {
    float4 a0 = *(const float4*)(L2g + r * 128 + u0);
    float4 a1 = *(const float4*)(L2g + r * 128 + u0 + 4);
    float4 b0 = *(const float4*)&Rs[r * 128 + v0];
    float4 b1 = *(const float4*)&Rs[r * 128 + 64 + v0];
    float av[8] = {a0.x, a0.y, a0.z, a0.w, a1.x, a1.y, a1.z, a1.w};
    float bv[8] = {b0.x, b0.y, b0.z, b0.w, b1.x, b1.y, b1.z, b1.w};
#pragma unroll
    for (int i = 0; i < 8; ++i)
#pragma unroll
      for (int j = 0; j < 8; ++j) acc[i][j] += av[i] * bv[j];
  }
  long base = (long)bo * 16384;
#pragma unroll
  for (int i = 0; i < 8; ++i) {
    float4 s0 = make_float4(acc[i][0], acc[i][1], acc[i][2], acc[i][3]);
    float4 s1 = make_float4(acc[i][4], acc[i][5], acc[i][6], acc[i][7]);
    *(float4*)&out[base + (u0 + i) * 128 + v0] = s0;
    *(float4*)&out[base + (u0 + i) * 128 + 64 + v0] = s1;
  }
}

extern "C" void kernel_launch(void* const* d_in, const int* in_sizes, int n_in,
                              void* d_out, int out_size, void* d_ws, size_t ws_size,
                              hipStream_t stream) {
  const float* x = (const float*)d_in[0];    // (16,64,128,128)
  const float* w1 = (const float*)d_in[1];   // (64,64,20,20)
  float* out = (float*)d_out;                // (16,64,128,128)
  float* ws = (float*)d_ws;

  float* Wp = ws;                  // 1,638,400
  float* Wm = Wp + 1638400;        // 1,638,400
  float* X1 = Wm + 1638400;        // 409,600
  float* O = X1 + 409600;          // 409,600
  float* wbT = O + 409600;         // 1,638,400
  float* Tg = wbT + 1638400;       // 5,120
  float* Lf2g = Tg + 5120;         // 10,240
  float* L2g = Lf2g + 10240;       // 5,376
  float* RB2g = L2g + 5376;        // 5,376   (total ~23 MB)

  hipLaunchKernelGGL(kinit, dim3(3), dim3(256), 0, stream, L2g, RB2g, Tg, Lf2g);
  hipLaunchKernelGGL(k0a_blurT, dim3(448), dim3(256), 0, stream, w1, wbT);
  hipLaunchKernelGGL(k0b_combine, dim3(400), dim3(256), 0, stream, wbT, Wp, Wm);
  hipLaunchKernelGGL(k12, dim3(1024), dim3(256), 0, stream, x, Tg, Lf2g, X1);
  hipLaunchKernelGGL(k3_mix, dim3(1600), dim3(256), 0, stream, X1, Wp, Wm, O);
  hipLaunchKernelGGL(k5b_final, dim3(1024), dim3(256), 0, stream, O, L2g, RB2g, out);
}

// Round 2
// 200.504 us; speedup vs baseline: 1.2484x; 1.1697x over previous
//
#include <hip/hip_runtime.h>

// SpectralConv2d DHT spectral conv, B=16, Cin=Cout=64, H=W=128, modes 20x20.
// All stages linear; blurs folded into bases/weights.
//   fwd:  X(k1,k2) = sum_n1 [cos(th k1 n1) Pc - sin(th k1 n1) Ps
//                            - sin(th k1(n1+1)) Pc1 - cos(th k1(n1+1)) Ps1]
//   inv (rank-42): y(u,v) = sum_{A=0..20} cosb(u,A)*RsC[A][v] + sinb(u,A)*RsS[A][v]
// Kernels (4 launches):
//  kA (451 blocks): blk0-2 = init tables (L2g/RB2g, Tg, Lf2g); blk3+ = w1 blur+T
//  k12: FUSED per (b,c). v3: float4 LDS staging (conflict-free, no swizzle needed
//       on xs), float4 scatter, 40960B LDS union -> 4 blocks/CU.
//  k3:  v3: k0b folded in algebraically (reads wbT directly, Xp/Xm pre-combined)
//  k5b: v2: Rs-build k2-outer (basis loaded once per k2, 5.7x less L1 traffic)

#define TWO_PI 6.283185307179586f
#define THETA (TWO_PI / 128.0f)

__device__ __forceinline__ void gauss9(float* g) {
  float s = 0.f;
#pragma unroll
  for (int t = 0; t < 9; ++t) { float d = (float)(t - 4); g[t] = expf(-0.5f * d * d); s += g[t]; }
  float inv = 1.f / s;
#pragma unroll
  for (int t = 0; t < 9; ++t) g[t] *= inv;
}

// ---- kA: blk0: L2g+RB2g (42x128), blk1: Tg, blk2: Lf2g, blk3..450: w1 blur+T
__global__ void kA_init(float* __restrict__ L2g, float* __restrict__ RB2g,
                        float* __restrict__ Tg, float* __restrict__ Lf2g,
                        const float* __restrict__ w1, float* __restrict__ wbT) {
  __shared__ float sh[5632];   // raw[128][44] (blk0) | tile[64][69] (blk>=3)
  int tid = threadIdx.x;
  int blk = blockIdx.x;
  if (blk == 1) {
    for (int i = tid; i < 5120; i += 256) {
      int n2 = i / 40, col = i - n2 * 40;
      int k2 = (col < 20) ? col : col - 20;
      float a = (float)((k2 * n2) & 127) * THETA;
      Tg[i] = (col < 20) ? cosf(a) : sinf(a);
    }
    return;
  }
  if (blk == 2) {
    for (int i = tid; i < 10240; i += 256) {
      int k1 = i >> 9, t = i & 511;
      int q = t >> 7, n1 = t & 127;
      int nn = n1 + ((q >= 2) ? 1 : 0);
      float a = (float)((k1 * nn) & 127) * THETA;
      float v;
      if (q == 0) v = cosf(a);
      else if (q == 1) v = -sinf(a);
      else if (q == 2) v = -sinf(a);
      else v = -cosf(a);
      Lf2g[i] = v;
    }
    return;
  }
  if (blk == 0) {
    // rank-42 bases. rows 0..20 = cos(th u A), 21..41 = sin(th u A)
    for (int i = tid; i < 5376; i += 256) {
      int u = i / 42, t = i - u * 42;
      int A = (t < 21) ? t : t - 21;
      float a = (float)((u * A) & 127) * THETA;
      sh[u * 44 + t] = (t < 21) ? cosf(a) : sinf(a);
    }
    __syncthreads();
    float g[9]; gauss9(g);
    for (int i = tid; i < 5376; i += 256) {
      int u = i / 42, t = i - u * 42;
      float acc = 0.f;
#pragma unroll
      for (int tp = 0; tp < 9; ++tp) {
        int uc = u - 4 + tp; uc = uc < 0 ? 0 : (uc > 127 ? 127 : uc);
        acc += g[tp] * sh[uc * 44 + t];
      }
      L2g[t * 128 + u] = acc;
      bool keep = (u <= 32) || (u >= 96);
      RB2g[t * 128 + u] = keep ? acc : 0.f;
    }
    return;
  }
  // blk >= 3: blur w1 over Cout + transpose: wbT[(c*400+m)*64+o]
  int bb = blk - 3;
  int c = bb / 7, chunk = bb % 7;
  int m0 = chunk * 64;
  int mw = 400 - m0; if (mw > 64) mw = 64;
  for (int t = tid; t < 4096; t += 256) {
    int o = t >> 6, mm = t & 63;
    sh[o * 69 + mm] = (mm < mw) ? w1[(c * 64 + o) * 400 + m0 + mm] : 0.f;
  }
  __syncthreads();
  float g[9]; gauss9(g);
  for (int t = tid; t < 4096; t += 256) {
    int mm = t >> 6, o = t & 63;
    if (mm >= mw) continue;
    float acc = 0.f;
#pragma unroll
    for (int tp = 0; tp < 9; ++tp) {
      int oc = o - 4 + tp; oc = oc < 0 ? 0 : (oc > 63 ? 63 : oc);
      acc += g[tp] * sh[oc * 69 + mm];
    }
    wbT[(c * 400 + m0 + mm) * 64 + o] = acc;
  }
}

// ---- k12 v3: fused forward transform + mode combine. One block per (b,c).
// LDS union (40960 B -> 4 blocks/CU):
//   phase 1: [0..5120) Tgs; [5120..9344) xs[32][132]
//   phase 2: [0..10240) Pm2 (20 x 512, chunk-XOR swizzle on k2 for combine reads)
// Staging: float4-granular LDS writes at chunk 33*n2l+n1g (33==1 mod 32 ->
// conflict-free across 32 lanes); 4 strided-coalesced global dword loads/task.
// Scatter: float4 writes, chunk (part/4+rg)^m permutation -> conflict-free.
__global__ void __launch_bounds__(256, 4) k12(const float* __restrict__ x,
                                              const float* __restrict__ Tg,
                                              const float* __restrict__ Lf2g,
                                              float* __restrict__ X1) {
  __shared__ float lds[10240];   // 40960 B
  int bc = blockIdx.x, tid = threadIdx.x;
  const float* xb = x + (long)bc * 16384;

  for (int t = tid; t < 5120; t += 256) lds[t] = Tg[t];

  int rg = tid & 31, cg = tid >> 5;   // 32 row-groups x 8 col-groups
  int r0 = rg * 4, c0 = cg * 5;
  float acc[4][5];
#pragma unroll
  for (int i = 0; i < 4; ++i)
#pragma unroll
    for (int j = 0; j < 5; ++j) acc[i][j] = 0.f;

  float* xs = lds + 5120;             // [32][132]
  for (int ch = 0; ch < 4; ++ch) {
    __syncthreads();
    // stage: task = (n1-quad, n2l); 4 coalesced global loads -> 1 b128 LDS write
    for (int t = tid; t < 1024; t += 256) {
      int n2l = t & 31, n1g = t >> 5;
      const float* gp = xb + n1g * 512 + ch * 32 + n2l;
      float4 v = make_float4(gp[0], gp[128], gp[256], gp[384]);
      *(float4*)&xs[n2l * 132 + n1g * 4] = v;
    }
    __syncthreads();
#pragma unroll 4
    for (int k = 0; k < 32; ++k) {
      float4 av = *(const float4*)&xs[k * 132 + r0];        // conflict-free b128
      const float* tr = lds + (ch * 32 + k) * 40 + c0;      // 2-addr broadcast
      float avv[4] = {av.x, av.y, av.z, av.w};
      float bvv[5] = {tr[0], tr[1], tr[2], tr[3], tr[4]};
#pragma unroll
      for (int i = 0; i < 4; ++i)
#pragma unroll
        for (int j = 0; j < 5; ++j) acc[i][j] += avv[i] * bvv[j];
    }
  }
  __syncthreads();
  // scatter acc into swizzled Pm2 (float4 per col; conflict-free permutation)
#pragma unroll
  for (int j = 0; j < 5; ++j) {
    int col = c0 + j;
    int k2 = (col < 20) ? col : col - 20;
    int part = (col < 20) ? 0 : 128;
    int m = ((k2 >> 1) & 7) << 2;
    float* row = lds + k2 * 512;
    *(float4*)&row[(part + r0) ^ m] =
        make_float4(acc[0][j], acc[1][j], acc[2][j], acc[3][j]);
  }
  __syncthreads();
  // rotation: Pc1/Ps1 = one-sample phase shift of Pc/Ps
  for (int t = tid; t < 2560; t += 256) {
    int k2 = t >> 7, n1 = t & 127;
    int m = ((k2 >> 1) & 7) << 2;
    float* row = lds + k2 * 512;
    float pc = row[n1 ^ m], ps = row[(128 + n1) ^ m];
    float ck, sk;
    sincosf(THETA * (float)k2, &sk, &ck);
    row[(256 + n1) ^ m] = ck * pc - sk * ps;
    row[(384 + n1) ^ m] = sk * pc + ck * ps;
  }
  __syncthreads();
  // combine: X1[k1][k2] = Lf2g[k1] . Pm2[k2]; 200 threads, 2 outputs each
  if (tid < 200) {
    int k1 = tid / 10, k2 = (tid % 10) * 2;
    int m = ((k2 >> 1) & 7) << 2;           // same for k2 and k2+1
    const float* p0r = lds + k2 * 512;
    const float* p1r = lds + (k2 + 1) * 512;
    const float* lrow = Lf2g + k1 * 512;
    float a0 = 0.f, a1 = 0.f;
    for (int t = 0; t < 512; t += 4) {
      float4 l = *(const float4*)(lrow + t);
      int ts = t ^ m;                       // chunk-aligned (m has only bits 2..4)
      float4 p0 = *(const float4*)(p0r + ts);
      float4 p1 = *(const float4*)(p1r + ts);
      a0 += l.x * p0.x + l.y * p0.y + l.z * p0.z + l.w * p0.w;
      a1 += l.x * p1.x + l.y * p1.y + l.z * p1.z + l.w * p1.w;
    }
    X1[(k1 * 20 + k2) * 1024 + bc] = a0;
    X1[(k1 * 20 + k2 + 1) * 1024 + bc] = a1;
  }
}

// ---- k3 v3: k0b folded in. grid (m*4 + bq). O[(b*64+o)*400+m]
// acc = sum_c wbT[c,m,o]*sc*(Xa+Xn)[c] + wbT[c,nm,o]*sc*(Xa-Xn)[c]
__global__ void k3_mix(const float* __restrict__ X1, const float* __restrict__ wbT,
                       float* __restrict__ O) {
  __shared__ float Xp[4][64], Xm[4][64];
  int m = blockIdx.x >> 2, bq = blockIdx.x & 3;
  int i = m / 20, j = m - i * 20;
  int nm = ((20 - i) % 20) * 20 + ((20 - j) % 20);
  int tid = threadIdx.x;
  const float sc = 0.5f / 16384.0f;
  float g[9]; gauss9(g);
  {
    int bl = tid >> 6, c = tid & 63;
    int b = bq * 4 + bl;
    float sa = 0.f, sn = 0.f;
#pragma unroll
    for (int tp = 0; tp < 9; ++tp) {
      int bb = b - 4 + tp; bb = bb < 0 ? 0 : (bb > 15 ? 15 : bb);
      sa += g[tp] * X1[m * 1024 + bb * 64 + c];
      sn += g[tp] * X1[nm * 1024 + bb * 64 + c];
    }
    Xp[bl][c] = (sa + sn) * sc; Xm[bl][c] = (sa - sn) * sc;
  }
  __syncthreads();
  int o = tid & 63, bl = tid >> 6;
  int b = bq * 4 + bl;
  float acc = 0.f;
#pragma unroll 4
  for (int c = 0; c < 64; ++c) {
    acc += wbT[(c * 400 + m) * 64 + o] * Xp[bl][c]
         + wbT[(c * 400 + nm) * 64 + o] * Xm[bl][c];
  }
  O[(b * 64 + o) * 400 + m] = acc;
}

// ---- k5b v2: per (b,o). Rs-build k2-outer: 7 rgroups x 32 vq, basis float4
// loaded once per k2 (coalesced L1), Os coeffs broadcast from LDS.
//   cos row A: + Os[A,k2]*Bc[k2] (k2<20,A<20)  - Os[A-1,k2-1]*Bs[k2] (k2>=1,A>=1)
//   sin row A: - Os[A,k2]*Bs[k2] (k2<20,A<20)  - Os[A-1,k2-1]*Bc[k2] (k2>=1,A>=1)
__global__ void __launch_bounds__(256) k5b_final(const float* __restrict__ O,
                                                 const float* __restrict__ L2g,
                                                 const float* __restrict__ RB2g,
                                                 float* __restrict__ out) {
  __shared__ float Os[400];
  __shared__ float Rs[42 * 128];
  int bo = blockIdx.x, tid = threadIdx.x;
  for (int t = tid; t < 400; t += 256) Os[t] = O[bo * 400 + t];
  __syncthreads();
  const float4* Bc4 = (const float4*)RB2g;             // rows 0..20
  const float4* Bs4 = (const float4*)(RB2g + 21 * 128);
  {
    int vq = tid & 31, rg = tid >> 5;   // rg 0..7; rg==7 idle (42 = 7*6 rows)
    if (rg < 7) {
      int r0 = rg * 6;
      float4 a[6];
#pragma unroll
      for (int i = 0; i < 6; ++i) a[i] = make_float4(0.f, 0.f, 0.f, 0.f);
      for (int k2 = 0; k2 <= 20; ++k2) {
        float4 bc = Bc4[k2 * 32 + vq];
        float4 bs = Bs4[k2 * 32 + vq];
#pragma unroll
        for (int i = 0; i < 6; ++i) {
          int r = r0 + i;
          bool isS = (r >= 21);
          int A = isS ? (r - 21) : r;
          if (k2 < 20 && A < 20) {
            float ov = Os[A * 20 + k2];
            const float4 b = isS ? bs : bc;
            float s = isS ? -ov : ov;
            a[i].x += s * b.x; a[i].y += s * b.y; a[i].z += s * b.z; a[i].w += s * b.w;
          }
          if (k2 >= 1 && A >= 1) {
            float ov = Os[(A - 1) * 20 + (k2 - 1)];
            const float4 b = isS ? bc : bs;
            a[i].x -= ov * b.x; a[i].y -= ov * b.y; a[i].z -= ov * b.z; a[i].w -= ov * b.w;
          }
        }
      }
#pragma unroll
      for (int i = 0; i < 6; ++i)
        *(float4*)&Rs[(r0 + i) * 128 + vq * 4] = a[i];
    }
  }
  __syncthreads();
  int ug = tid >> 4, vg = tid & 15;
  int u0 = ug * 8, v0 = vg * 4;   // v-cols: v0..v0+3 and 64+v0..64+v0+3
  float acc[8][8];
#pragma unroll
  for (int i = 0; i < 8; ++i)
#pragma unroll
    for (int j = 0; j < 8; ++j) acc[i][j] = 0.f;
  for (int r = 0; r < 42; ++r) {
    float4 a0 = *(const float4*)(L2g + r * 128 + u0);
    float4 a1 = *(const float4*)(L2g + r * 128 + u0 + 4);
    float4 b0 = *(const float4*)&Rs[r * 128 + v0];
    float4 b1 = *(const float4*)&Rs[r * 128 + 64 + v0];
    float av[8] = {a0.x, a0.y, a0.z, a0.w, a1.x, a1.y, a1.z, a1.w};
    float bv[8] = {b0.x, b0.y, b0.z, b0.w, b1.x, b1.y, b1.z, b1.w};
#pragma unroll
    for (int i = 0; i < 8; ++i)
#pragma unroll
      for (int j = 0; j < 8; ++j) acc[i][j] += av[i] * bv[j];
  }
  long base = (long)bo * 16384;
#pragma unroll
  for (int i = 0; i < 8; ++i) {
    float4 s0 = make_float4(acc[i][0], acc[i][1], acc[i][2], acc[i][3]);
    float4 s1 = make_float4(acc[i][4], acc[i][5], acc[i][6], acc[i][7]);
    *(float4*)&out[base + (u0 + i) * 128 + v0] = s0;
    *(float4*)&out[base + (u0 + i) * 128 + 64 + v0] = s1;
  }
}

extern "C" void kernel_launch(void* const* d_in, const int* in_sizes, int n_in,
                              void* d_out, int out_size, void* d_ws, size_t ws_size,
                              hipStream_t stream) {
  const float* x = (const float*)d_in[0];    // (16,64,128,128)
  const float* w1 = (const float*)d_in[1];   // (64,64,20,20)
  float* out = (float*)d_out;                // (16,64,128,128)
  float* ws = (float*)d_ws;

  float* X1 = ws;                  // 409,600
  float* O = X1 + 409600;          // 409,600
  float* wbT = O + 409600;         // 1,638,400
  float* Tg = wbT + 1638400;       // 5,120
  float* Lf2g = Tg + 5120;         // 10,240
  float* L2g = Lf2g + 10240;       // 5,376
  float* RB2g = L2g + 5376;        // 5,376   (total ~10 MB)

  hipLaunchKernelGGL(kA_init, dim3(451), dim3(256), 0, stream,
                     L2g, RB2g, Tg, Lf2g, w1, wbT);
  hipLaunchKernelGGL(k12, dim3(1024), dim3(256), 0, stream, x, Tg, Lf2g, X1);
  hipLaunchKernelGGL(k3_mix, dim3(1600), dim3(256), 0, stream, X1, wbT, O);
  hipLaunchKernelGGL(k5b_final, dim3(1024), dim3(256), 0, stream, O, L2g, RB2g, out);
}

// Round 3
// 197.128 us; speedup vs baseline: 1.2698x; 1.0171x over previous
//
#include <hip/hip_runtime.h>

// SpectralConv2d DHT spectral conv, B=16, Cin=Cout=64, H=W=128, modes 20x20.
// All stages linear; blurs folded into bases/weights.
//   fwd:  X(k1,k2) = sum_n1 [cos(th k1 n1) Pc - sin(th k1 n1) Ps
//                            - sin(th k1(n1+1)) Pc1 - cos(th k1(n1+1)) Ps1]
//        rotation folded:  X1 = D0 + D1 + ck*(D2c+D3s) + sk*(D3c-D2s)
//   inv (rank-42): y(u,v) = sum_{A=0..20} cosb(u,A)*RsC[A][v] + sinb(u,A)*RsS[A][v]
// Kernels (4 launches):
//  kA (451 blocks): blk0-2 = init tables (L2g/RB2g, Tg, Lf2g); blk3+ = w1 blur+T
//  k12 v4: per (b,c), 320 thr (5 waves x 8 cols). B-operand via wave-uniform
//       s_load (no LDS), A via ds_read_b64; rotation folded into combine;
//       LDS = max(xs, Pm2) = 20480 B -> 6 blocks/CU.
//  k3:  k0b folded in algebraically (reads wbT directly, Xp/Xm pre-combined)
//  k5b: Rs-build k2-outer (basis loaded once per k2)

#define TWO_PI 6.283185307179586f
#define THETA (TWO_PI / 128.0f)

__device__ __forceinline__ void gauss9(float* g) {
  float s = 0.f;
#pragma unroll
  for (int t = 0; t < 9; ++t) { float d = (float)(t - 4); g[t] = expf(-0.5f * d * d); s += g[t]; }
  float inv = 1.f / s;
#pragma unroll
  for (int t = 0; t < 9; ++t) g[t] *= inv;
}

// ---- kA: blk0: L2g+RB2g (42x128), blk1: Tg, blk2: Lf2g, blk3..450: w1 blur+T
__global__ void kA_init(float* __restrict__ L2g, float* __restrict__ RB2g,
                        float* __restrict__ Tg, float* __restrict__ Lf2g,
                        const float* __restrict__ w1, float* __restrict__ wbT) {
  __shared__ float sh[5632];   // raw[128][44] (blk0) | tile[64][69] (blk>=3)
  int tid = threadIdx.x;
  int blk = blockIdx.x;
  if (blk == 1) {
    for (int i = tid; i < 5120; i += 256) {
      int n2 = i / 40, col = i - n2 * 40;
      int k2 = (col < 20) ? col : col - 20;
      float a = (float)((k2 * n2) & 127) * THETA;
      Tg[i] = (col < 20) ? cosf(a) : sinf(a);
    }
    return;
  }
  if (blk == 2) {
    for (int i = tid; i < 10240; i += 256) {
      int k1 = i >> 9, t = i & 511;
      int q = t >> 7, n1 = t & 127;
      int nn = n1 + ((q >= 2) ? 1 : 0);
      float a = (float)((k1 * nn) & 127) * THETA;
      float v;
      if (q == 0) v = cosf(a);
      else if (q == 1) v = -sinf(a);
      else if (q == 2) v = -sinf(a);
      else v = -cosf(a);
      Lf2g[i] = v;
    }
    return;
  }
  if (blk == 0) {
    // rank-42 bases. rows 0..20 = cos(th u A), 21..41 = sin(th u A)
    for (int i = tid; i < 5376; i += 256) {
      int u = i / 42, t = i - u * 42;
      int A = (t < 21) ? t : t - 21;
      float a = (float)((u * A) & 127) * THETA;
      sh[u * 44 + t] = (t < 21) ? cosf(a) : sinf(a);
    }
    __syncthreads();
    float g[9]; gauss9(g);
    for (int i = tid; i < 5376; i += 256) {
      int u = i / 42, t = i - u * 42;
      float acc = 0.f;
#pragma unroll
      for (int tp = 0; tp < 9; ++tp) {
        int uc = u - 4 + tp; uc = uc < 0 ? 0 : (uc > 127 ? 127 : uc);
        acc += g[tp] * sh[uc * 44 + t];
      }
      L2g[t * 128 + u] = acc;
      bool keep = (u <= 32) || (u >= 96);
      RB2g[t * 128 + u] = keep ? acc : 0.f;
    }
    return;
  }
  // blk >= 3: blur w1 over Cout + transpose: wbT[(c*400+m)*64+o]
  int bb = blk - 3;
  int c = bb / 7, chunk = bb % 7;
  int m0 = chunk * 64;
  int mw = 400 - m0; if (mw > 64) mw = 64;
  for (int t = tid; t < 4096; t += 256) {
    int o = t >> 6, mm = t & 63;
    sh[o * 69 + mm] = (mm < mw) ? w1[(c * 64 + o) * 400 + m0 + mm] : 0.f;
  }
  __syncthreads();
  float g[9]; gauss9(g);
  for (int t = tid; t < 4096; t += 256) {
    int mm = t >> 6, o = t & 63;
    if (mm >= mw) continue;
    float acc = 0.f;
#pragma unroll
    for (int tp = 0; tp < 9; ++tp) {
      int oc = o - 4 + tp; oc = oc < 0 ? 0 : (oc > 63 ? 63 : oc);
      acc += g[tp] * sh[oc * 69 + mm];
    }
    wbT[(c * 400 + m0 + mm) * 64 + o] = acc;
  }
}

// ---- k12 v4: fused forward transform + mode combine. One block per (b,c).
// 320 threads = 5 waves; wave w owns cols 8w..8w+7, lane L owns rows 2L,2L+1.
// B-operand: Tg row slice via wave-uniform pointer (readfirstlane) -> s_load,
// zero LDS traffic. A-operand: ds_read_b64 from xs (stride-132 pad).
// Phase 2: scatter Pc/Ps (20x256, XOR-swizzled), then 6-dot separable combine
// (rotation coefficients ck/sk applied at epilogue; no rotation pass).
// LDS: xs[32][132]=16.9KB (phase1) overlaps Pm2[20][256]=20KB (phase2) -> 20480B.
__global__ void __launch_bounds__(320, 6) k12(const float* __restrict__ x,
                                              const float* __restrict__ Tg,
                                              const float* __restrict__ Lf2g,
                                              float* __restrict__ X1) {
  __shared__ float lds[5120];   // 20480 B
  int bc = blockIdx.x, tid = threadIdx.x;
  int w = __builtin_amdgcn_readfirstlane(tid >> 6);   // wave id 0..4 (uniform)
  int L = tid & 63;
  const float* xb = x + (long)bc * 16384;
  const float* tgw = Tg + w * 8;                      // wave-uniform base

  float acc[2][8];
#pragma unroll
  for (int i = 0; i < 2; ++i)
#pragma unroll
    for (int j = 0; j < 8; ++j) acc[i][j] = 0.f;

  for (int ch = 0; ch < 4; ++ch) {
    __syncthreads();
    // stage 128 n1 x 32 n2 transposed: 4 strided-coalesced loads -> 1 b128 write
    for (int t = tid; t < 1024; t += 320) {
      int n2l = t & 31, n1g = t >> 5;
      const float* gp = xb + n1g * 512 + ch * 32 + n2l;
      float4 v = make_float4(gp[0], gp[128], gp[256], gp[384]);
      *(float4*)&lds[n2l * 132 + n1g * 4] = v;
    }
    __syncthreads();
#pragma unroll 4
    for (int k = 0; k < 32; ++k) {
      float2 av = *(const float2*)&lds[k * 132 + 2 * L];     // rows 2L,2L+1
      const float* tr = tgw + (ch * 32 + k) * 40;            // uniform -> s_load
      float4 b0 = *(const float4*)tr;
      float4 b1 = *(const float4*)(tr + 4);
      float bv[8] = {b0.x, b0.y, b0.z, b0.w, b1.x, b1.y, b1.z, b1.w};
#pragma unroll
      for (int j = 0; j < 8; ++j) {
        acc[0][j] += av.x * bv[j];
        acc[1][j] += av.y * bv[j];
      }
    }
  }
  __syncthreads();
  // scatter into Pm2[20][256]: [0..128) Pc, [128..256) Ps; XOR swz (k2&7)<<2
#pragma unroll
  for (int j = 0; j < 8; ++j) {
    int col = w * 8 + j;
    int k2 = (col < 20) ? col : col - 20;
    int part = (col < 20) ? 0 : 128;
    int m = (k2 & 7) << 2;
    *(float2*)&lds[k2 * 256 + ((part + 2 * L) ^ m)] =
        make_float2(acc[0][j], acc[1][j]);
  }
  __syncthreads();
  // combine: 200 threads, 2 outputs (k2, k2+1) each; 6 separable dots
  if (tid < 200) {
    int k1 = tid / 10, k2 = (tid % 10) * 2;
    int m0 = (k2 & 7) << 2, m1 = ((k2 + 1) & 7) << 2;
    const float* lrow = Lf2g + k1 * 512;
    const float* p0 = lds + k2 * 256;
    const float* p1 = lds + (k2 + 1) * 256;
    float d0a = 0.f, d1a = 0.f, d2ca = 0.f, d2sa = 0.f, d3ca = 0.f, d3sa = 0.f;
    float d0b = 0.f, d1b = 0.f, d2cb = 0.f, d2sb = 0.f, d3cb = 0.f, d3sb = 0.f;
    for (int t = 0; t < 128; t += 4) {
      float4 l0 = *(const float4*)(lrow + t);
      float4 l1 = *(const float4*)(lrow + 128 + t);
      float4 l2 = *(const float4*)(lrow + 256 + t);
      float4 l3 = *(const float4*)(lrow + 384 + t);
      float4 pc0 = *(const float4*)(p0 + (t ^ m0));
      float4 ps0 = *(const float4*)(p0 + ((128 + t) ^ m0));
      float4 pc1 = *(const float4*)(p1 + (t ^ m1));
      float4 ps1 = *(const float4*)(p1 + ((128 + t) ^ m1));
      d0a += l0.x*pc0.x + l0.y*pc0.y + l0.z*pc0.z + l0.w*pc0.w;
      d1a += l1.x*ps0.x + l1.y*ps0.y + l1.z*ps0.z + l1.w*ps0.w;
      d2ca += l2.x*pc0.x + l2.y*pc0.y + l2.z*pc0.z + l2.w*pc0.w;
      d2sa += l2.x*ps0.x + l2.y*ps0.y + l2.z*ps0.z + l2.w*ps0.w;
      d3ca += l3.x*pc0.x + l3.y*pc0.y + l3.z*pc0.z + l3.w*pc0.w;
      d3sa += l3.x*ps0.x + l3.y*ps0.y + l3.z*ps0.z + l3.w*ps0.w;
      d0b += l0.x*pc1.x + l0.y*pc1.y + l0.z*pc1.z + l0.w*pc1.w;
      d1b += l1.x*ps1.x + l1.y*ps1.y + l1.z*ps1.z + l1.w*ps1.w;
      d2cb += l2.x*pc1.x + l2.y*pc1.y + l2.z*pc1.z + l2.w*pc1.w;
      d2sb += l2.x*ps1.x + l2.y*ps1.y + l2.z*ps1.z + l2.w*ps1.w;
      d3cb += l3.x*pc1.x + l3.y*pc1.y + l3.z*pc1.z + l3.w*pc1.w;
      d3sb += l3.x*ps1.x + l3.y*ps1.y + l3.z*ps1.z + l3.w*ps1.w;
    }
    float ska, cka, skb, ckb;
    sincosf(THETA * (float)k2, &ska, &cka);
    sincosf(THETA * (float)(k2 + 1), &skb, &ckb);
    X1[(k1 * 20 + k2) * 1024 + bc] = d0a + d1a + cka * (d2ca + d3sa) + ska * (d3ca - d2sa);
    X1[(k1 * 20 + k2 + 1) * 1024 + bc] = d0b + d1b + ckb * (d2cb + d3sb) + skb * (d3cb - d2sb);
  }
}

// ---- k3: k0b folded in. grid (m*4 + bq). O[(b*64+o)*400+m]
// acc = sum_c wbT[c,m,o]*sc*(Xa+Xn)[c] + wbT[c,nm,o]*sc*(Xa-Xn)[c]
__global__ void k3_mix(const float* __restrict__ X1, const float* __restrict__ wbT,
                       float* __restrict__ O) {
  __shared__ float Xp[4][64], Xm[4][64];
  int m = blockIdx.x >> 2, bq = blockIdx.x & 3;
  int i = m / 20, j = m - i * 20;
  int nm = ((20 - i) % 20) * 20 + ((20 - j) % 20);
  int tid = threadIdx.x;
  const float sc = 0.5f / 16384.0f;
  float g[9]; gauss9(g);
  {
    int bl = tid >> 6, c = tid & 63;
    int b = bq * 4 + bl;
    float sa = 0.f, sn = 0.f;
#pragma unroll
    for (int tp = 0; tp < 9; ++tp) {
      int bb = b - 4 + tp; bb = bb < 0 ? 0 : (bb > 15 ? 15 : bb);
      sa += g[tp] * X1[m * 1024 + bb * 64 + c];
      sn += g[tp] * X1[nm * 1024 + bb * 64 + c];
    }
    Xp[bl][c] = (sa + sn) * sc; Xm[bl][c] = (sa - sn) * sc;
  }
  __syncthreads();
  int o = tid & 63, bl = tid >> 6;
  int b = bq * 4 + bl;
  float acc = 0.f;
#pragma unroll 4
  for (int c = 0; c < 64; ++c) {
    acc += wbT[(c * 400 + m) * 64 + o] * Xp[bl][c]
         + wbT[(c * 400 + nm) * 64 + o] * Xm[bl][c];
  }
  O[(b * 64 + o) * 400 + m] = acc;
}

// ---- k5b: per (b,o). Rs-build k2-outer: 7 rgroups x 32 vq, basis float4
// loaded once per k2 (coalesced L1), Os coeffs broadcast from LDS.
__global__ void __launch_bounds__(256) k5b_final(const float* __restrict__ O,
                                                 const float* __restrict__ L2g,
                                                 const float* __restrict__ RB2g,
                                                 float* __restrict__ out) {
  __shared__ float Os[400];
  __shared__ float Rs[42 * 128];
  int bo = blockIdx.x, tid = threadIdx.x;
  for (int t = tid; t < 400; t += 256) Os[t] = O[bo * 400 + t];
  __syncthreads();
  const float4* Bc4 = (const float4*)RB2g;             // rows 0..20
  const float4* Bs4 = (const float4*)(RB2g + 21 * 128);
  {
    int vq = tid & 31, rg = tid >> 5;   // rg 0..7; rg==7 idle (42 = 7*6 rows)
    if (rg < 7) {
      int r0 = rg * 6;
      float4 a[6];
#pragma unroll
      for (int i = 0; i < 6; ++i) a[i] = make_float4(0.f, 0.f, 0.f, 0.f);
      for (int k2 = 0; k2 <= 20; ++k2) {
        float4 bc = Bc4[k2 * 32 + vq];
        float4 bs = Bs4[k2 * 32 + vq];
#pragma unroll
        for (int i = 0; i < 6; ++i) {
          int r = r0 + i;
          bool isS = (r >= 21);
          int A = isS ? (r - 21) : r;
          if (k2 < 20 && A < 20) {
            float ov = Os[A * 20 + k2];
            const float4 b = isS ? bs : bc;
            float s = isS ? -ov : ov;
            a[i].x += s * b.x; a[i].y += s * b.y; a[i].z += s * b.z; a[i].w += s * b.w;
          }
          if (k2 >= 1 && A >= 1) {
            float ov = Os[(A - 1) * 20 + (k2 - 1)];
            const float4 b = isS ? bc : bs;
            a[i].x -= ov * b.x; a[i].y -= ov * b.y; a[i].z -= ov * b.z; a[i].w -= ov * b.w;
          }
        }
      }
#pragma unroll
      for (int i = 0; i < 6; ++i)
        *(float4*)&Rs[(r0 + i) * 128 + vq * 4] = a[i];
    }
  }
  __syncthreads();
  int ug = tid >> 4, vg = tid & 15;
  int u0 = ug * 8, v0 = vg * 4;   // v-cols: v0..v0+3 and 64+v0..64+v0+3
  float acc[8][8];
#pragma unroll
  for (int i = 0; i < 8; ++i)
#pragma unroll
    for (int j = 0; j < 8; ++j) acc[i][j] = 0.f;
  for (int r = 0; r < 42; ++r) {
    float4 a0 = *(const float4*)(L2g + r * 128 + u0);
    float4 a1 = *(const float4*)(L2g + r * 128 + u0 + 4);
    float4 b0 = *(const float4*)&Rs[r * 128 + v0];
    float4 b1 = *(const float4*)&Rs[r * 128 + 64 + v0];
    float av[8] = {a0.x, a0.y, a0.z, a0.w, a1.x, a1.y, a1.z, a1.w};
    float bv[8] = {b0.x, b0.y, b0.z, b0.w, b1.x, b1.y, b1.z, b1.w};
#pragma unroll
    for (int i = 0; i < 8; ++i)
#pragma unroll
      for (int j = 0; j < 8; ++j) acc[i][j] += av[i] * bv[j];
  }
  long base = (long)bo * 16384;
#pragma unroll
  for (int i = 0; i < 8; ++i) {
    float4 s0 = make_float4(acc[i][0], acc[i][1], acc[i][2], acc[i][3]);
    float4 s1 = make_float4(acc[i][4], acc[i][5], acc[i][6], acc[i][7]);
    *(float4*)&out[base + (u0 + i) * 128 + v0] = s0;
    *(float4*)&out[base + (u0 + i) * 128 + 64 + v0] = s1;
  }
}

extern "C" void kernel_launch(void* const* d_in, const int* in_sizes, int n_in,
                              void* d_out, int out_size, void* d_ws, size_t ws_size,
                              hipStream_t stream) {
  const float* x = (const float*)d_in[0];    // (16,64,128,128)
  const float* w1 = (const float*)d_in[1];   // (64,64,20,20)
  float* out = (float*)d_out;                // (16,64,128,128)
  float* ws = (float*)d_ws;

  float* X1 = ws;                  // 409,600
  float* O = X1 + 409600;          // 409,600
  float* wbT = O + 409600;         // 1,638,400
  float* Tg = wbT + 1638400;       // 5,120
  float* Lf2g = Tg + 5120;         // 10,240
  float* L2g = Lf2g + 10240;       // 5,376
  float* RB2g = L2g + 5376;        // 5,376   (total ~10 MB)

  hipLaunchKernelGGL(kA_init, dim3(451), dim3(256), 0, stream,
                     L2g, RB2g, Tg, Lf2g, w1, wbT);
  hipLaunchKernelGGL(k12, dim3(1024), dim3(320), 0, stream, x, Tg, Lf2g, X1);
  hipLaunchKernelGGL(k3_mix, dim3(1600), dim3(256), 0, stream, X1, wbT, O);
  hipLaunchKernelGGL(k5b_final, dim3(1024), dim3(256), 0, stream, O, L2g, RB2g, out);
}